// Round 1
// baseline (1284.576 us; speedup 1.0000x reference)
//
#include <hip/hip_runtime.h>

#define B_ 2
#define N_ 4096
#define M_ 32
#define D_ 128
#define E_ 64
#define LN_EPS 1e-5f

// ---------------------------------------------------------------------------
// Kernel 1: per-(b,n) projections.
//   q[bn][e][0:3) = sum_d x1[bn][d][ml] * to_queries[d][e]   (ml=0..2)
//   q[bn][e][3:8) = sum_d x2[bn][d][ml] * to_queries[d][e]   (ml=0..4)
//   k[bn][e][0:3) uses to_keys1, k[bn][e][3:8) uses to_keys2
// Layout in workspace: [bn][e][8] floats (32 B per (bn,e) -> one dwordx4 x2)
// ---------------------------------------------------------------------------
__global__ __launch_bounds__(64) void proj_kernel(
    const float* __restrict__ x1, const float* __restrict__ x2,
    const float* __restrict__ Wq, const float* __restrict__ Wk1,
    const float* __restrict__ Wk2,
    float* __restrict__ qws, float* __restrict__ kws)
{
    const int bn = blockIdx.x;          // 0 .. B*N-1
    const int e  = threadIdx.x;         // 0 .. 63
    __shared__ float x1s[D_ * 3];
    __shared__ float x2s[D_ * 5];
    const float* x1p = x1 + (size_t)bn * (D_ * 3);
    const float* x2p = x2 + (size_t)bn * (D_ * 5);
    for (int i = e; i < D_ * 3; i += 64) x1s[i] = x1p[i];
    for (int i = e; i < D_ * 5; i += 64) x2s[i] = x2p[i];
    __syncthreads();

    float q[8] = {0.f,0.f,0.f,0.f,0.f,0.f,0.f,0.f};
    float k[8] = {0.f,0.f,0.f,0.f,0.f,0.f,0.f,0.f};
    #pragma unroll 4
    for (int d = 0; d < D_; ++d) {
        const float wq  = Wq [d * E_ + e];   // coalesced across lanes
        const float wk1 = Wk1[d * E_ + e];
        const float wk2 = Wk2[d * E_ + e];
        #pragma unroll
        for (int ml = 0; ml < 3; ++ml) {
            const float xv = x1s[d * 3 + ml];      // LDS broadcast
            q[ml] += xv * wq;
            k[ml] += xv * wk1;
        }
        #pragma unroll
        for (int ml = 0; ml < 5; ++ml) {
            const float xv = x2s[d * 5 + ml];
            q[3 + ml] += xv * wq;
            k[3 + ml] += xv * wk2;
        }
    }
    float* qo = qws + ((size_t)bn * E_ + e) * 8;
    float* ko = kws + ((size_t)bn * E_ + e) * 8;
    #pragma unroll
    for (int s = 0; s < 8; ++s) { qo[s] = q[s]; ko[s] = k[s]; }
}

// ---------------------------------------------------------------------------
// Kernel 2: per-(b,n) fused edge pipeline. 256 threads = 2 groups of 128.
// Group g handles j = g*16 .. g*16+15, in 4 blocks of 4 j (register blocking
// so each LDS weight read feeds 4 FMAs). Thread c in a group owns output
// channel c for all 4 j.
// LDS: edge_w + res_w fp32 (128 KiB) + wn/tl staging (8 KiB) -> 1 block/CU.
// ---------------------------------------------------------------------------
__global__ __launch_bounds__(256) void fused_kernel(
    const float* __restrict__ t_ij, const int* __restrict__ nidx,
    const float* __restrict__ qws, const float* __restrict__ kws,
    const float* __restrict__ ln_w, const float* __restrict__ edge_w,
    const float* __restrict__ res_w, float* __restrict__ out)
{
    __shared__ float  ew[D_ * D_];      // edge_w [e][dout], 64 KiB
    __shared__ float  rw[D_ * D_];      // res_w  [d][eout], 64 KiB
    __shared__ float4 wn4[2][D_];       // normalized w, [group][e] -> 4 j
    __shared__ float4 tl4[2][D_];       // t_ij tile,   [group][d] -> 4 j
    __shared__ float  red[2][4][2][2];  // [group][jj][wave][sum, sumsq]

    const int t   = threadIdx.x;
    const int c   = t & 127;            // output channel
    const int g   = t >> 7;             // group 0/1
    const int wig = (t >> 6) & 1;       // wave-in-group
    const int bn  = blockIdx.x;
    const int b   = bn >> 12;           // bn / N_

    for (int i = t; i < D_ * D_; i += 256) { ew[i] = edge_w[i]; rw[i] = res_w[i]; }

    // per-thread q fragment (wave-uniform branch: lanes 0..63 have c<64)
    const int  e_idx = c & 63;
    const bool lo    = (c < 64);
    const float* qp  = qws + ((size_t)bn * E_ + e_idx) * 8;
    float qreg[5];
    if (lo) {
        qreg[0] = qp[0]; qreg[1] = qp[1]; qreg[2] = qp[2];
        qreg[3] = 0.f;   qreg[4] = 0.f;
    } else {
        qreg[0] = qp[3]; qreg[1] = qp[4]; qreg[2] = qp[5];
        qreg[3] = qp[6]; qreg[4] = qp[7];
    }
    const float  lnwc  = ln_w[c];
    const size_t jbase = (size_t)bn * M_;
    __syncthreads();

    for (int jb = 0; jb < 4; ++jb) {
        const int j0 = g * 16 + jb * 4;

        // stage t_ij for the group's 4 j (coalesced reads, transposed write)
        float4 tv;
        tv.x = t_ij[(jbase + j0 + 0) * D_ + c];
        tv.y = t_ij[(jbase + j0 + 1) * D_ + c];
        tv.z = t_ij[(jbase + j0 + 2) * D_ + c];
        tv.w = t_ij[(jbase + j0 + 3) * D_ + c];
        tl4[g][c] = tv;

        // raw w values: inner product over multiplicity slots
        float wv[4];
        #pragma unroll
        for (int jj = 0; jj < 4; ++jj) {
            const int nj = nidx[jbase + j0 + jj];
            const float* kp = kws + (((size_t)b * N_ + nj) * E_ + e_idx) * 8;
            float acc;
            if (lo) {
                acc = qreg[0] * kp[0] + qreg[1] * kp[1] + qreg[2] * kp[2];
            } else {
                acc = qreg[0] * kp[3] + qreg[1] * kp[4] + qreg[2] * kp[5]
                    + qreg[3] * kp[6] + qreg[4] * kp[7];
            }
            wv[jj] = acc;
        }

        // LayerNorm stats over the 128-thread group (2 waves)
        #pragma unroll
        for (int jj = 0; jj < 4; ++jj) {
            float s  = wv[jj];
            float s2 = wv[jj] * wv[jj];
            #pragma unroll
            for (int off = 1; off < 64; off <<= 1) {
                s  += __shfl_xor(s,  off, 64);
                s2 += __shfl_xor(s2, off, 64);
            }
            if ((t & 63) == 0) { red[g][jj][wig][0] = s; red[g][jj][wig][1] = s2; }
        }
        __syncthreads();

        float4 wnv;
        {
            float* w = (float*)&wnv;
            #pragma unroll
            for (int jj = 0; jj < 4; ++jj) {
                const float s   = red[g][jj][0][0] + red[g][jj][1][0];
                const float s2  = red[g][jj][0][1] + red[g][jj][1][1];
                const float mu  = s * (1.f / 128.f);
                const float var = fmaxf(s2 * (1.f / 128.f) - mu * mu, 0.f);
                const float r   = rsqrtf(var + LN_EPS);
                w[jj] = (wv[jj] - mu) * r * lnwc;
            }
        }
        wn4[g][c] = wnv;
        __syncthreads();

        // two 128x128 matmuls, 4 j per weight read
        float ea0=0.f, ea1=0.f, ea2=0.f, ea3=0.f;
        float ra0=0.f, ra1=0.f, ra2=0.f, ra3=0.f;
        #pragma unroll 4
        for (int i = 0; i < D_; ++i) {
            const float  evv = ew[i * D_ + c];   // 2 lanes/bank: conflict-free
            const float  rvv = rw[i * D_ + c];
            const float4 w4  = wn4[g][i];        // broadcast b128
            const float4 t4  = tl4[g][i];
            ea0 += w4.x * evv; ea1 += w4.y * evv; ea2 += w4.z * evv; ea3 += w4.w * evv;
            ra0 += t4.x * rvv; ra1 += t4.y * rvv; ra2 += t4.z * rvv; ra3 += t4.w * rvv;
        }
        const float eo[4] = {ea0, ea1, ea2, ea3};
        const float ro[4] = {ra0, ra1, ra2, ra3};
        #pragma unroll
        for (int jj = 0; jj < 4; ++jj) {
            const float sg = 1.f / (1.f + __expf(-eo[jj]));
            out[(jbase + j0 + jj) * D_ + c] = sg + ro[jj];
        }
        __syncthreads();   // protect wn4/tl4/red before next jb
    }
}

extern "C" void kernel_launch(void* const* d_in, const int* in_sizes, int n_in,
                              void* d_out, int out_size, void* d_ws, size_t ws_size,
                              hipStream_t stream) {
    const float* t_ij = (const float*)d_in[0];
    const float* x1   = (const float*)d_in[1];
    const float* x2   = (const float*)d_in[2];
    const int*   nidx = (const int*)  d_in[3];
    const float* Wq   = (const float*)d_in[4];
    const float* Wk1  = (const float*)d_in[5];
    const float* Wk2  = (const float*)d_in[6];
    const float* lnw  = (const float*)d_in[7];
    const float* eww  = (const float*)d_in[8];
    const float* rww  = (const float*)d_in[9];
    float* out = (float*)d_out;

    // workspace: q then k, each B*N*E*8 floats = 16.78 MB (33.55 MB total)
    float* qws = (float*)d_ws;
    float* kws = qws + (size_t)B_ * N_ * E_ * 8;

    proj_kernel<<<B_ * N_, 64, 0, stream>>>(x1, x2, Wq, Wk1, Wk2, qws, kws);
    fused_kernel<<<B_ * N_, 256, 0, stream>>>(t_ij, nidx, qws, kws, lnw, eww, rww, out);
}

// Round 2
// 518.102 us; speedup vs baseline: 2.4794x; 2.4794x over previous
//
#include <hip/hip_runtime.h>

#define B_ 2
#define N_ 4096
#define M_ 32
#define D_ 128
#define E_ 64
#define LN_EPS 1e-5f
#define WSTRIDE 136   // bf16 elems/row: 272 B -> 16B-aligned rows, bank-advance 4 (2-way, free)

typedef __bf16 bf16x8 __attribute__((ext_vector_type(8)));
typedef float  f32x4  __attribute__((ext_vector_type(4)));

// ---------------------------------------------------------------------------
// Kernel 1: projections. One wave per bn, 4 bn per 256-thr block.
// x values are wave-uniform -> scalar (s_load) path; weight rows are the only
// vector loads. q/k layout in ws: [bn][e][8] fp32, slots {x1:0..2, x2:3..7}.
// ---------------------------------------------------------------------------
__global__ __launch_bounds__(256) void proj_kernel(
    const float* __restrict__ x1, const float* __restrict__ x2,
    const float* __restrict__ Wq, const float* __restrict__ Wk1,
    const float* __restrict__ Wk2,
    float* __restrict__ qws, float* __restrict__ kws)
{
    const int lane = threadIdx.x & 63;
    const int wv   = threadIdx.x >> 6;
    const int bn   = __builtin_amdgcn_readfirstlane(blockIdx.x * 4 + wv);

    const float* __restrict__ x1p = x1 + (size_t)bn * (D_ * 3);
    const float* __restrict__ x2p = x2 + (size_t)bn * (D_ * 5);

    float q[8] = {0.f,0.f,0.f,0.f,0.f,0.f,0.f,0.f};
    float k[8] = {0.f,0.f,0.f,0.f,0.f,0.f,0.f,0.f};

    #pragma unroll 4
    for (int d = 0; d < D_; ++d) {
        const float wq  = Wq [d * E_ + lane];
        const float wk1 = Wk1[d * E_ + lane];
        const float wk2 = Wk2[d * E_ + lane];
        #pragma unroll
        for (int ml = 0; ml < 3; ++ml) {
            const float xv = x1p[d * 3 + ml];   // wave-uniform -> scalar load
            q[ml] += xv * wq;
            k[ml] += xv * wk1;
        }
        #pragma unroll
        for (int ml = 0; ml < 5; ++ml) {
            const float xv = x2p[d * 5 + ml];   // wave-uniform -> scalar load
            q[3 + ml] += xv * wq;
            k[3 + ml] += xv * wk2;
        }
    }
    float4* qo = (float4*)(qws + ((size_t)bn * E_ + lane) * 8);
    float4* ko = (float4*)(kws + ((size_t)bn * E_ + lane) * 8);
    qo[0] = make_float4(q[0], q[1], q[2], q[3]);
    qo[1] = make_float4(q[4], q[5], q[6], q[7]);
    ko[0] = make_float4(k[0], k[1], k[2], k[3]);
    ko[1] = make_float4(k[4], k[5], k[6], k[7]);
}

// ---------------------------------------------------------------------------
// Kernel 2: fused edge pipeline with bf16 MFMA matmuls.
// 256 threads/block, grid-stride over bn (4 per block).
// LDS: ewT[d][e], rwT[e_out][d] bf16 transposed (B-operand layout) + wbuf.
// Per bn: phase W (raw w -> LDS bf16), phase S (LayerNorm in place),
// phase M (each wave: 16 rows x 64 cols of BOTH matmuls, fused epilogue).
// ---------------------------------------------------------------------------
__global__ __launch_bounds__(256) void fused_mfma(
    const float* __restrict__ t_ij, const int* __restrict__ nidx,
    const float* __restrict__ qws, const float* __restrict__ kws,
    const float* __restrict__ ln_w, const float* __restrict__ edge_w,
    const float* __restrict__ res_w, float* __restrict__ out)
{
    __shared__ __bf16 ewT[D_ * WSTRIDE];   // ewT[d_out][e_k] = edge_w[e_k][d_out]
    __shared__ __bf16 rwT[D_ * WSTRIDE];   // rwT[e_out][d_k] = res_w[d_k][e_out]
    __shared__ __bf16 wbuf[M_ * WSTRIDE];  // w_ij tile, raw then normalized

    const int t    = threadIdx.x;
    const int lane = t & 63;

    // ---- stage weights once per block: fp32 -> bf16, transposed ----
    for (int i = t; i < (D_ * D_) / 4; i += 256) {
        const float4 ve = ((const float4*)edge_w)[i];
        const float4 vr = ((const float4*)res_w)[i];
        const int row = i >> 5;          // source row (k index)
        const int c0  = (i & 31) * 4;    // source col (n index)
        ewT[(c0 + 0) * WSTRIDE + row] = (__bf16)ve.x;
        ewT[(c0 + 1) * WSTRIDE + row] = (__bf16)ve.y;
        ewT[(c0 + 2) * WSTRIDE + row] = (__bf16)ve.z;
        ewT[(c0 + 3) * WSTRIDE + row] = (__bf16)ve.w;
        rwT[(c0 + 0) * WSTRIDE + row] = (__bf16)vr.x;
        rwT[(c0 + 1) * WSTRIDE + row] = (__bf16)vr.y;
        rwT[(c0 + 2) * WSTRIDE + row] = (__bf16)vr.z;
        rwT[(c0 + 3) * WSTRIDE + row] = (__bf16)vr.w;
    }

    // phase S constants: thread handles j=jS, channels sS*16..+16
    const int jS = t >> 3;
    const int sS = t & 7;
    float lnr[16];
    {
        const float* lp = ln_w + sS * 16;
        #pragma unroll
        for (int i = 0; i < 4; ++i) {
            const float4 v = ((const float4*)lp)[i];
            lnr[i*4+0] = v.x; lnr[i*4+1] = v.y; lnr[i*4+2] = v.z; lnr[i*4+3] = v.w;
        }
    }

    // phase W mapping: c = t&127, h = t>>7 (j-half)
    const int  cW = t & 127;
    const int  hW = t >> 7;
    const bool lo = (cW < 64);
    const int  eW = cW & 63;

    // phase M mapping: wave -> (m-tile, n-half)
    const int wvM   = t >> 6;
    const int mW    = (wvM & 1) * 16;
    const int nHalf = (wvM >> 1) * 64;
    const int r16   = lane & 15;
    const int quad  = lane >> 4;

    for (int bn = blockIdx.x; bn < B_ * N_; bn += gridDim.x) {
        const int    b  = bn >> 12;
        const size_t jb = (size_t)bn * M_;
        __syncthreads();   // wbuf (and, first iter, ewT/rwT) ready / consumed

        // ---------------- phase W: raw w_ij ----------------
        const float* qp = qws + ((size_t)bn * E_ + eW) * 8;
        float4 qa; float q3 = 0.f;
        if (lo) { qa = *(const float4*)qp; }
        else    { qa = *(const float4*)(qp + 4); q3 = qp[3]; }

        #pragma unroll 4
        for (int jj = 0; jj < 16; ++jj) {
            const int j  = hW * 16 + jj;
            const int nj = nidx[jb + j];
            const float* kp = kws + (((size_t)b * N_ + nj) * E_ + eW) * 8;
            float w;
            if (lo) {
                const float4 ka = *(const float4*)kp;
                w = qa.x * ka.x + qa.y * ka.y + qa.z * ka.z;
            } else {
                const float4 ka = *(const float4*)(kp + 4);
                w = q3 * kp[3] + qa.x * ka.x + qa.y * ka.y
                  + qa.z * ka.z + qa.w * ka.w;
            }
            wbuf[j * WSTRIDE + cW] = (__bf16)w;
        }
        __syncthreads();

        // ---------------- phase S: LayerNorm in place ----------------
        {
            __bf16* wp = &wbuf[jS * WSTRIDE + sS * 16];
            bf16x8 v0 = *(bf16x8*)wp;
            bf16x8 v1 = *(bf16x8*)(wp + 8);
            float f[16];
            #pragma unroll
            for (int i = 0; i < 8; ++i) { f[i] = (float)v0[i]; f[8+i] = (float)v1[i]; }
            float s1 = 0.f, s2 = 0.f;
            #pragma unroll
            for (int i = 0; i < 16; ++i) { s1 += f[i]; s2 += f[i] * f[i]; }
            #pragma unroll
            for (int off = 1; off < 8; off <<= 1) {
                s1 += __shfl_xor(s1, off, 64);
                s2 += __shfl_xor(s2, off, 64);
            }
            const float mu  = s1 * (1.f / 128.f);
            const float var = fmaxf(s2 * (1.f / 128.f) - mu * mu, 0.f);
            const float rs  = rsqrtf(var + LN_EPS);
            #pragma unroll
            for (int i = 0; i < 8; ++i) {
                v0[i] = (__bf16)((f[i]   - mu) * rs * lnr[i]);
                v1[i] = (__bf16)((f[8+i] - mu) * rs * lnr[8+i]);
            }
            *(bf16x8*)wp       = v0;
            *(bf16x8*)(wp + 8) = v1;
        }
        __syncthreads();

        // ---------------- phase M: MFMA matmuls + epilogue ----------------
        f32x4 accE[4], accR[4];
        #pragma unroll
        for (int nt = 0; nt < 4; ++nt) {
            accE[nt] = (f32x4){0.f, 0.f, 0.f, 0.f};
            accR[nt] = (f32x4){0.f, 0.f, 0.f, 0.f};
        }
        const float* tp = t_ij + (jb + mW + r16) * D_;
        #pragma unroll
        for (int ks = 0; ks < 4; ++ks) {
            const int kb = ks * 32 + quad * 8;
            const bf16x8 aE = *(bf16x8*)&wbuf[(mW + r16) * WSTRIDE + kb];
            const float4 t0 = *(const float4*)(tp + kb);
            const float4 t1 = *(const float4*)(tp + kb + 4);
            bf16x8 aR;
            aR[0] = (__bf16)t0.x; aR[1] = (__bf16)t0.y;
            aR[2] = (__bf16)t0.z; aR[3] = (__bf16)t0.w;
            aR[4] = (__bf16)t1.x; aR[5] = (__bf16)t1.y;
            aR[6] = (__bf16)t1.z; aR[7] = (__bf16)t1.w;
            #pragma unroll
            for (int nt = 0; nt < 4; ++nt) {
                const int n0 = (nHalf + nt * 16 + r16) * WSTRIDE + kb;
                const bf16x8 bE = *(bf16x8*)&ewT[n0];
                const bf16x8 bR = *(bf16x8*)&rwT[n0];
                accE[nt] = __builtin_amdgcn_mfma_f32_16x16x32_bf16(aE, bE, accE[nt], 0, 0, 0);
                accR[nt] = __builtin_amdgcn_mfma_f32_16x16x32_bf16(aR, bR, accR[nt], 0, 0, 0);
            }
        }
        #pragma unroll
        for (int nt = 0; nt < 4; ++nt) {
            #pragma unroll
            for (int rr = 0; rr < 4; ++rr) {
                const int row = mW + quad * 4 + rr;
                const int col = nHalf + nt * 16 + r16;
                const float e  = accE[nt][rr];
                const float sg = 1.f / (1.f + __expf(-e));
                out[(jb + row) * D_ + col] = sg + accR[nt][rr];
            }
        }
    }
}

extern "C" void kernel_launch(void* const* d_in, const int* in_sizes, int n_in,
                              void* d_out, int out_size, void* d_ws, size_t ws_size,
                              hipStream_t stream) {
    const float* t_ij = (const float*)d_in[0];
    const float* x1   = (const float*)d_in[1];
    const float* x2   = (const float*)d_in[2];
    const int*   nidx = (const int*)  d_in[3];
    const float* Wq   = (const float*)d_in[4];
    const float* Wk1  = (const float*)d_in[5];
    const float* Wk2  = (const float*)d_in[6];
    const float* lnw  = (const float*)d_in[7];
    const float* eww  = (const float*)d_in[8];
    const float* rww  = (const float*)d_in[9];
    float* out = (float*)d_out;

    float* qws = (float*)d_ws;                       // [bn][e][8] fp32
    float* kws = qws + (size_t)B_ * N_ * E_ * 8;     // [bn][e][8] fp32

    proj_kernel<<<(B_ * N_) / 4, 256, 0, stream>>>(x1, x2, Wq, Wk1, Wk2, qws, kws);
    fused_mfma<<<2048, 256, 0, stream>>>(t_ij, nidx, qws, kws, lnw, eww, rww, out);
}

// Round 4
// 384.828 us; speedup vs baseline: 3.3380x; 1.3463x over previous
//
#include <hip/hip_runtime.h>

#define B_ 2
#define N_ 4096
#define M_ 32
#define D_ 128
#define E_ 64
#define LN_EPS 1e-5f
#define WST 136              // bf16 elems/row of w-tile: 272B rows, 16B-aligned
#define TOT (B_ * N_)

typedef __bf16 bf16x8 __attribute__((ext_vector_type(8)));
typedef float  f32x4  __attribute__((ext_vector_type(4)));

// ---------------------------------------------------------------------------
// K1: projections. One wave per bn (4 bn / 256-thr block). x staged in LDS
// packed [d][8] so the d-loop does 2 broadcast ds_read_b128 instead of 8
// scalar loads. q stored fp32 [bn][e][8]; k stored bf16 [bn][e][8].
// Slots: 0..2 = x1(ml0..2), 3..7 = x2(ml0..4).
// ---------------------------------------------------------------------------
__global__ __launch_bounds__(256) void proj_kernel(
    const float* __restrict__ x1, const float* __restrict__ x2,
    const float* __restrict__ Wq, const float* __restrict__ Wk1,
    const float* __restrict__ Wk2,
    float* __restrict__ qws, __bf16* __restrict__ kws)
{
    __shared__ float xs[4][D_ * 8];
    const int lane = threadIdx.x & 63;
    const int wv   = threadIdx.x >> 6;
    const int bn   = blockIdx.x * 4 + wv;
    float* xw = xs[wv];
    const float* __restrict__ x1p = x1 + (size_t)bn * (D_ * 3);
    const float* __restrict__ x2p = x2 + (size_t)bn * (D_ * 5);
    for (int i = lane; i < D_ * 3; i += 64) xw[(i / 3) * 8 + (i % 3)]     = x1p[i];
    for (int i = lane; i < D_ * 5; i += 64) xw[(i / 5) * 8 + 3 + (i % 5)] = x2p[i];
    __syncthreads();

    float q[8] = {0.f,0.f,0.f,0.f,0.f,0.f,0.f,0.f};
    float k[8] = {0.f,0.f,0.f,0.f,0.f,0.f,0.f,0.f};
    #pragma unroll 4
    for (int d = 0; d < D_; ++d) {
        const float4 xa = *(const float4*)&xw[d * 8];       // broadcast b128
        const float4 xb = *(const float4*)&xw[d * 8 + 4];
        const float wq  = Wq [d * E_ + lane];
        const float wk1 = Wk1[d * E_ + lane];
        const float wk2 = Wk2[d * E_ + lane];
        q[0] += xa.x * wq;  q[1] += xa.y * wq;  q[2] += xa.z * wq;  q[3] += xa.w * wq;
        q[4] += xb.x * wq;  q[5] += xb.y * wq;  q[6] += xb.z * wq;  q[7] += xb.w * wq;
        k[0] += xa.x * wk1; k[1] += xa.y * wk1; k[2] += xa.z * wk1;
        k[3] += xa.w * wk2; k[4] += xb.x * wk2; k[5] += xb.y * wk2;
        k[6] += xb.z * wk2; k[7] += xb.w * wk2;
    }
    float4* qo = (float4*)(qws + ((size_t)bn * E_ + lane) * 8);
    qo[0] = make_float4(q[0], q[1], q[2], q[3]);
    qo[1] = make_float4(q[4], q[5], q[6], q[7]);
    bf16x8 kb;
    #pragma unroll
    for (int s = 0; s < 8; ++s) kb[s] = (__bf16)k[s];
    *(bf16x8*)(kws + ((size_t)bn * E_ + lane) * 8) = kb;
}

// ---------------------------------------------------------------------------
// K2: fused gather + LN + dual MFMA matmul + epilogue.
// Persistent 768 blocks (3/CU), grid-stride over bn. B-fragments of both
// weight matrices built once per block from fp32 globals, kept in registers
// (64 VGPR). LDS = triple-buffered 32x136 bf16 w-tile only (25.5 KB).
// Pipeline per bn: phaseW(next) -> barrier -> phaseM(curr) -> tload(next).
// Triple buffer + single barrier is race-free: a write to buffer X in iter
// i+3k is separated from the prior read of X by >=1 full-block barrier.
// ---------------------------------------------------------------------------
__global__ __launch_bounds__(256, 3) void fused_kernel(
    const float* __restrict__ t_ij, const int* __restrict__ nidx,
    const float* __restrict__ qws, const __bf16* __restrict__ kws,
    const float* __restrict__ ln_w,
    const float* __restrict__ edge_w, const float* __restrict__ res_w,
    float* __restrict__ out)
{
    __shared__ __bf16 wbuf[3][M_ * WST];

    const int t    = threadIdx.x;
    const int lane = t & 63;
    const int wvu  = t >> 6;
    const int r16  = lane & 15;
    const int quad = lane >> 4;
    const int n0   = wvu * 32;          // this wave's 32-col output slice

    // ---- persistent B-fragments (fp32 global -> bf16 regs), one-time ----
    // B[k][n]: lane holds k = ks*32 + quad*8 + j, n = n0 + nt*16 + r16.
    bf16x8 bE[2][4], bR[2][4];
    #pragma unroll
    for (int nt = 0; nt < 2; ++nt) {
        const int col = n0 + nt * 16 + r16;
        #pragma unroll
        for (int ks = 0; ks < 4; ++ks) {
            const int k0 = ks * 32 + quad * 8;
            bf16x8 fe, fr;
            #pragma unroll
            for (int j = 0; j < 8; ++j) {
                fe[j] = (__bf16)edge_w[(k0 + j) * D_ + col];
                fr[j] = (__bf16)res_w [(k0 + j) * D_ + col];
            }
            bE[nt][ks] = fe;
            bR[nt][ks] = fr;
        }
    }

    const float lnlo = ln_w[lane];
    const float lnhi = ln_w[64 + lane];

    // ---- phase W: compute+LN 8 j-rows of w into an LDS buffer ----
    auto phaseW = [&](int bn, __bf16* buf) {
        const int    b  = bn >> 12;
        const size_t jb = (size_t)bn * M_;
        const float* qp = qws + ((size_t)bn * E_ + lane) * 8;
        const float4 qa = *(const float4*)qp;
        const float4 qb = *(const float4*)(qp + 4);
        #pragma unroll 4
        for (int jj = 0; jj < 8; ++jj) {
            const int j  = wvu * 8 + jj;
            const int nj = nidx[jb + j];
            const bf16x8 kv =
                *(const bf16x8*)&kws[((size_t)(b * N_ + nj) * E_ + lane) * 8];
            const float wlo = qa.x * (float)kv[0] + qa.y * (float)kv[1]
                            + qa.z * (float)kv[2];
            const float whi = qa.w * (float)kv[3] + qb.x * (float)kv[4]
                            + qb.y * (float)kv[5] + qb.z * (float)kv[6]
                            + qb.w * (float)kv[7];
            float s1 = wlo + whi;
            float s2 = wlo * wlo + whi * whi;
            #pragma unroll
            for (int off = 1; off < 64; off <<= 1) {
                s1 += __shfl_xor(s1, off, 64);
                s2 += __shfl_xor(s2, off, 64);
            }
            const float mu  = s1 * (1.f / 128.f);
            const float var = fmaxf(s2 * (1.f / 128.f) - mu * mu, 0.f);
            const float rs  = rsqrtf(var + LN_EPS);
            buf[j * WST + lane]      = (__bf16)((wlo - mu) * rs * lnlo);
            buf[j * WST + 64 + lane] = (__bf16)((whi - mu) * rs * lnhi);
        }
    };

    // ---- t_ij prefetch for mt=0 rows (r16), packed to bf16 A-frags ----
    auto tload = [&](int bn, bf16x8* tf) {
        const float* tp = t_ij + ((size_t)bn * M_ + r16) * D_;
        #pragma unroll
        for (int ks = 0; ks < 4; ++ks) {
            const int ko = ks * 32 + quad * 8;
            const float4 t0 = *(const float4*)(tp + ko);
            const float4 t1 = *(const float4*)(tp + ko + 4);
            bf16x8 a;
            a[0]=(__bf16)t0.x; a[1]=(__bf16)t0.y; a[2]=(__bf16)t0.z; a[3]=(__bf16)t0.w;
            a[4]=(__bf16)t1.x; a[5]=(__bf16)t1.y; a[6]=(__bf16)t1.z; a[7]=(__bf16)t1.w;
            tf[ks] = a;
        }
    };

    // ---- phase M: dual matmul for this wave's 32 cols + fused epilogue ----
    auto phaseM = [&](int bn, const __bf16* buf, const bf16x8* tf) {
        const size_t jb = (size_t)bn * M_;
        // mt=1 t_ij rows: load + convert immediately (keeps VGPR low)
        bf16x8 aT1[4];
        {
            const float* tp = t_ij + (jb + 16 + r16) * D_;
            #pragma unroll
            for (int ks = 0; ks < 4; ++ks) {
                const int ko = ks * 32 + quad * 8;
                const float4 t0 = *(const float4*)(tp + ko);
                const float4 t1 = *(const float4*)(tp + ko + 4);
                bf16x8 a;
                a[0]=(__bf16)t0.x; a[1]=(__bf16)t0.y; a[2]=(__bf16)t0.z; a[3]=(__bf16)t0.w;
                a[4]=(__bf16)t1.x; a[5]=(__bf16)t1.y; a[6]=(__bf16)t1.z; a[7]=(__bf16)t1.w;
                aT1[ks] = a;
            }
        }
        f32x4 accE[2][2], accR[2][2];
        #pragma unroll
        for (int mt = 0; mt < 2; ++mt)
            #pragma unroll
            for (int nt = 0; nt < 2; ++nt) {
                accE[mt][nt] = (f32x4){0.f,0.f,0.f,0.f};
                accR[mt][nt] = (f32x4){0.f,0.f,0.f,0.f};
            }
        #pragma unroll
        for (int ks = 0; ks < 4; ++ks) {
            const bf16x8 aW0 = *(const bf16x8*)&buf[r16 * WST + ks * 32 + quad * 8];
            const bf16x8 aW1 = *(const bf16x8*)&buf[(16 + r16) * WST + ks * 32 + quad * 8];
            #pragma unroll
            for (int nt = 0; nt < 2; ++nt) {
                accE[0][nt] = __builtin_amdgcn_mfma_f32_16x16x32_bf16(aW0,    bE[nt][ks], accE[0][nt], 0, 0, 0);
                accR[0][nt] = __builtin_amdgcn_mfma_f32_16x16x32_bf16(tf[ks], bR[nt][ks], accR[0][nt], 0, 0, 0);
                accE[1][nt] = __builtin_amdgcn_mfma_f32_16x16x32_bf16(aW1,    bE[nt][ks], accE[1][nt], 0, 0, 0);
                accR[1][nt] = __builtin_amdgcn_mfma_f32_16x16x32_bf16(aT1[ks],bR[nt][ks], accR[1][nt], 0, 0, 0);
            }
        }
        // epilogue: sigmoid(edge) + res, store fp32
        #pragma unroll
        for (int mt = 0; mt < 2; ++mt)
            #pragma unroll
            for (int nt = 0; nt < 2; ++nt)
                #pragma unroll
                for (int rr = 0; rr < 4; ++rr) {
                    const int row = mt * 16 + quad * 4 + rr;
                    const int col = n0 + nt * 16 + r16;
                    const float e  = accE[mt][nt][rr];
                    const float sg = 1.f / (1.f + __expf(-e));
                    out[(jb + row) * D_ + col] = sg + accR[mt][nt][rr];
                }
    };

    // ---- main pipeline: W(next) -> barrier -> M(curr) -> tload(next) ----
    const int stride = gridDim.x;
    int bn = blockIdx.x;
    bf16x8 tf[4];
    phaseW(bn, wbuf[0]);
    tload(bn, tf);
    int buf = 0;
    for (; bn < TOT; bn += stride) {
        const int nb   = bn + stride;
        const int nbuf = (buf == 2) ? 0 : buf + 1;
        if (nb < TOT) phaseW(nb, wbuf[nbuf]);
        __syncthreads();
        phaseM(bn, wbuf[buf], tf);
        if (nb < TOT) tload(nb, tf);
        buf = nbuf;
    }
}

extern "C" void kernel_launch(void* const* d_in, const int* in_sizes, int n_in,
                              void* d_out, int out_size, void* d_ws, size_t ws_size,
                              hipStream_t stream) {
    const float* t_ij = (const float*)d_in[0];
    const float* x1   = (const float*)d_in[1];
    const float* x2   = (const float*)d_in[2];
    const int*   nidx = (const int*)  d_in[3];
    const float* Wq   = (const float*)d_in[4];
    const float* Wk1  = (const float*)d_in[5];
    const float* Wk2  = (const float*)d_in[6];
    const float* lnw  = (const float*)d_in[7];
    const float* eww  = (const float*)d_in[8];
    const float* rww  = (const float*)d_in[9];
    float* out = (float*)d_out;

    // ws layout: qws fp32 [bn][e][8] (16.78 MB) | kws bf16 [bn][e][8] (8.39 MB)
    float*  qws = (float*)d_ws;
    __bf16* kws = (__bf16*)(qws + (size_t)TOT * E_ * 8);

    proj_kernel<<<TOT / 4, 256, 0, stream>>>(x1, x2, Wq, Wk1, Wk2, qws, kws);
    fused_kernel<<<768, 256, 0, stream>>>(t_ij, nidx, qws, kws, lnw, eww, rww, out);
}